// Round 13
// baseline (119.656 us; speedup 1.0000x reference)
//
#include <hip/hip_runtime.h>
#include <math.h>

#define BS   8192
#define DIM  256
#define KNEG 16
#define GAMMA (1.0f / 0.07f)
#define EXP_CLAMP 60.0f   // e^60*8192*16 ~ 1.5e31 < FLT_MAX: sums stay finite
#define NSTRIPS 8

typedef float v4f  __attribute__((ext_vector_type(4)));
typedef short s8b  __attribute__((ext_vector_type(8)));   // 8 bf16 as shorts
typedef _Float16 h2 __attribute__((ext_vector_type(2)));  // packed pair (ni0, ni1)

__device__ __forceinline__ float sat_exp(float dot) {
    float a = 2.0f * GAMMA * dot - 2.0f * GAMMA;
    return expf(fminf(a, EXP_CLAMP));
}

// pack two f32 -> two f16 (v_cvt_pkrtz_f16_f32), bit-cast to our h2 type
__device__ __forceinline__ h2 pk2(float a, float b) {
    return __builtin_bit_cast(h2, __builtin_amdgcn_cvt_pkrtz(a, b));
}

// compare-exchange: x=min, y=max (2 VALU, no selects)
__device__ __forceinline__ void ce(float& x, float& y) {
    float lo = fminf(x, y), hi = fmaxf(x, y);
    x = lo; y = hi;
}

// packed compare-exchange: both halves independently (v_pk_min/max_f16)
__device__ __forceinline__ void ce2(h2& x, h2& y) {
    h2 lo = __builtin_elementwise_min(x, y);
    h2 hi = __builtin_elementwise_max(x, y);
    x = lo; y = hi;
}

// Batcher odd-even merge sort, 16 packed inputs, ascending per half. 63 CE.
__device__ __forceinline__ void sort16p(h2 (&a)[16]) {
    ce2(a[0],a[1]); ce2(a[2],a[3]); ce2(a[4],a[5]); ce2(a[6],a[7]);
    ce2(a[8],a[9]); ce2(a[10],a[11]); ce2(a[12],a[13]); ce2(a[14],a[15]);
    ce2(a[0],a[2]); ce2(a[1],a[3]); ce2(a[4],a[6]); ce2(a[5],a[7]);
    ce2(a[8],a[10]); ce2(a[9],a[11]); ce2(a[12],a[14]); ce2(a[13],a[15]);
    ce2(a[1],a[2]); ce2(a[5],a[6]); ce2(a[9],a[10]); ce2(a[13],a[14]);
    ce2(a[0],a[4]); ce2(a[1],a[5]); ce2(a[2],a[6]); ce2(a[3],a[7]);
    ce2(a[8],a[12]); ce2(a[9],a[13]); ce2(a[10],a[14]); ce2(a[11],a[15]);
    ce2(a[2],a[4]); ce2(a[3],a[5]); ce2(a[10],a[12]); ce2(a[11],a[13]);
    ce2(a[1],a[2]); ce2(a[3],a[4]); ce2(a[5],a[6]);
    ce2(a[9],a[10]); ce2(a[11],a[12]); ce2(a[13],a[14]);
    ce2(a[0],a[8]); ce2(a[1],a[9]); ce2(a[2],a[10]); ce2(a[3],a[11]);
    ce2(a[4],a[12]); ce2(a[5],a[13]); ce2(a[6],a[14]); ce2(a[7],a[15]);
    ce2(a[4],a[8]); ce2(a[5],a[9]); ce2(a[6],a[10]); ce2(a[7],a[11]);
    ce2(a[2],a[4]); ce2(a[3],a[5]); ce2(a[6],a[8]); ce2(a[7],a[9]);
    ce2(a[10],a[12]); ce2(a[11],a[13]);
    ce2(a[1],a[2]); ce2(a[3],a[4]); ce2(a[5],a[6]); ce2(a[7],a[8]);
    ce2(a[9],a[10]); ce2(a[11],a[12]); ce2(a[13],a[14]);
}

// merge two ascending sorted-16 (packed), keep top-16 ascending (16 max + 32 CE)
__device__ __forceinline__ void merge2_top16(h2 (&lst)[16], const h2 (&nw)[16]) {
#pragma unroll
    for (int i = 0; i < 16; ++i)
        lst[i] = __builtin_elementwise_max(lst[i], nw[15 - i]);
#pragma unroll
    for (int j = 8; j > 0; j >>= 1)
#pragma unroll
        for (int i = 0; i < 16; ++i) {
            int ixj = i ^ j;
            if (ixj > i) ce2(lst[i], lst[ixj]);
        }
}

// f32 merge kept for stage2 (reads f32 workspace lists)
__device__ __forceinline__ void merge_top16(float (&lst)[16], const float (&nw)[16]) {
#pragma unroll
    for (int i = 0; i < 16; ++i) lst[i] = fmaxf(lst[i], nw[15 - i]);
#pragma unroll
    for (int j = 8; j > 0; j >>= 1)
#pragma unroll
        for (int i = 0; i < 16; ++i) {
            int ixj = i ^ j;
            if (ixj > i) ce(lst[i], lst[ixj]);
        }
}

// legacy insertion helper (fallback path only)
__device__ __forceinline__ void topk_insert(float (&lst)[16], float v) {
    float nl[16];
#pragma unroll
    for (int u = 0; u < 15; ++u)
        nl[u] = (v > lst[u + 1]) ? lst[u + 1] : ((v > lst[u]) ? v : lst[u]);
    nl[15] = (v > lst[15]) ? v : lst[15];
#pragma unroll
    for (int u = 0; u < 16; ++u) lst[u] = nl[u];
}

__device__ __forceinline__ unsigned short f2bf_rne(float f) {
    unsigned int u = __float_as_uint(f);
    u += 0x7FFFu + ((u >> 16) & 1u);
    return (unsigned short)(u >> 16);
}

__device__ __forceinline__ void gld_lds16(const void* g, void* l) {
    __builtin_amdgcn_global_load_lds(
        (const __attribute__((address_space(1))) void*)g,
        (__attribute__((address_space(3))) void*)l, 16, 0, 0);
}

__device__ __forceinline__ float finite_or(float x, float repl) {
    if (isnan(x)) return repl;
    if (isinf(x)) return x > 0.0f ? 3.0e38f : -3.0e38f;
    return x;
}

__device__ __forceinline__ h2 shfl2(h2 x, int src) {
    float f = __builtin_bit_cast(float, x);
    f = __shfl(f, src, 64);
    return __builtin_bit_cast(h2, f);
}

// ------- conv_pos: fp32 -> bf16 pre-convert + per-block diagonal partials -----
__global__ void conv_pos(const float* __restrict__ feat,
                         unsigned short* __restrict__ featbf,
                         float* __restrict__ partialPos) {
    __shared__ float red[8];
    int t = blockIdx.x * 256 + threadIdx.x;   // 0..262143
    int row = t >> 5;
    int c = t & 31;                           // 8-float chunk within the 256-dim
    const float* f1 = feat + (size_t)row * 512 + c * 8;
    const float* f2 = f1 + 256;
    float4 a0 = *(const float4*)(f1);
    float4 a1 = *(const float4*)(f1 + 4);
    float4 b0 = *(const float4*)(f2);
    float4 b1 = *(const float4*)(f2 + 4);
    uint4 pa, pb;
    pa.x = (unsigned)f2bf_rne(a0.x) | ((unsigned)f2bf_rne(a0.y) << 16);
    pa.y = (unsigned)f2bf_rne(a0.z) | ((unsigned)f2bf_rne(a0.w) << 16);
    pa.z = (unsigned)f2bf_rne(a1.x) | ((unsigned)f2bf_rne(a1.y) << 16);
    pa.w = (unsigned)f2bf_rne(a1.z) | ((unsigned)f2bf_rne(a1.w) << 16);
    pb.x = (unsigned)f2bf_rne(b0.x) | ((unsigned)f2bf_rne(b0.y) << 16);
    pb.y = (unsigned)f2bf_rne(b0.z) | ((unsigned)f2bf_rne(b0.w) << 16);
    pb.z = (unsigned)f2bf_rne(b1.x) | ((unsigned)f2bf_rne(b1.y) << 16);
    pb.w = (unsigned)f2bf_rne(b1.z) | ((unsigned)f2bf_rne(b1.w) << 16);
    *(uint4*)(featbf + (size_t)row * 512 + c * 8) = pa;
    *(uint4*)(featbf + (size_t)row * 512 + 256 + c * 8) = pb;
    float p = a0.x * b0.x + a0.y * b0.y + a0.z * b0.z + a0.w * b0.w
            + a1.x * b1.x + a1.y * b1.y + a1.z * b1.z + a1.w * b1.w;
#pragma unroll
    for (int o = 16; o; o >>= 1) p += __shfl_xor(p, o, 32);
    if (c == 0) red[threadIdx.x >> 5] = sat_exp(p);
    __syncthreads();
    if (threadIdx.x == 0) {
        float s = 0.0f;
#pragma unroll
        for (int i = 0; i < 8; ++i) s += red[i];
        partialPos[blockIdx.x] = s;
    }
}

// ---------------- stage1: R9 counted-vmcnt loop in 32KB LDS (occupancy 2x) --
// Block 256 thr = 4 waves (wy=row-half, wx=col-half). 16x16x32 MFMA.
// B (64 F1 rows x K=256, 32KB xor-swizzled) staged, frags hoisted to regs;
// then ALL THREE rotating 8KB A buffers live inside the dead B region
// (24KB < 32KB), so total LDS = 32KB -> 5 blocks/CU (was 48KB -> 3).
// launch_bounds stays (256,3): register allocation identical to the verified
// R9/R10 kernels (no R6-style unified-file split/spill). Occupancy cap rises
// 12 -> 20 waves/CU; the 64 per-block barrier convoys (R9's weakness at 22%
// occupancy) now overlap with other resident blocks' work (m114 mechanism).
// Prologue reorder (the enabler): stage B -> barrier -> hoist bfr -> barrier
// -> issue batch0,1 into dead-B buffers. Per batch: s_waitcnt vmcnt(2);
// s_barrier -> batch bs landed in all waves (wait is per-wave, barrier makes
// it collective); issue bs+2 into the buffer read 2 batches ago; 8 MFMA.
// vmcnt retires oldest-first (m135). Tail issues clamped dummy prefetches;
// epilogue __syncthreads drains them before merge-scratch reuse.
#define S1_LDS 32768

__global__ __launch_bounds__(256, 3) void stage1(const unsigned short* __restrict__ featbf,
                                                 float* __restrict__ wsTop) {
    __shared__ __align__(16) char smem[S1_LDS];
    const int t = threadIdx.x;
    const int l = t & 63;
    const int w = t >> 6;
    const int wy = w >> 1, wx = w & 1;
    const int quad = l >> 4, lane16 = l & 15;
    const int nbase = blockIdx.x * 64;
    const int strip = blockIdx.y;
    // diagonal lives only in this strip/ct (64 rows never straddle a 128-col ct)
    const bool dstrip = (strip == (nbase >> 10));
    const int dct = (nbase & 1023) >> 7;

    // ---- stage B resident: rows nbase..nbase+63 (F1), all K, swizzled ----
#pragma unroll
    for (int jj = 0; jj < 8; ++jj) {
        int j = w * 8 + jj;
        int r = 2 * j + (l >> 5);
        int c = (l & 31) ^ (r & 31);
        gld_lds16(featbf + ((size_t)(nbase + r) << 9) + c * 8, smem + j * 1024);
    }

    h2 lst[16];
    const h2 NINF = __builtin_bit_cast(h2, 0xFC00FC00u);   // (-inf, -inf)
#pragma unroll
    for (int i = 0; i < 16; ++i) lst[i] = NINF;

    const int akey = (quad ^ ((lane16 >> 1) & 3)) * 16;   // A frag slot offset
    const int sj_r = l >> 2;                              // A staging row-in-group
    const int sj_s = l & 3;                               // A staging slot

    __syncthreads();         // B staged (drains vmcnt to 0)

    // ---- B fragments -> registers, once ----
    s8b bfr[16];   // [ni*8 + s]
#pragma unroll
    for (int ni = 0; ni < 2; ++ni) {
        const int n31 = ni * 16 + lane16;
#pragma unroll
        for (int s = 0; s < 8; ++s)
            bfr[ni * 8 + s] = *(const s8b*)(smem
                + (wy * 32 + n31) * 512 + (((s * 4 + quad) ^ n31) & 31) * 16);
    }

    __syncthreads();         // all waves done reading B -> entire region aliasable

    // 3 rotating A buffers (8KB each), ALL inside the dead B region
    char* cur = smem;            // holds batch gs
    char* nxt = smem + 8192;     // holds gs+1
    char* fre = smem + 16384;    // free

    // stage one 128x32 A batch (global step gsn in [0,64)) into dst (2/wave)
    auto stageA = [&](int gsn, char* dst) {
        const int nct = strip * 1024 + (gsn >> 3) * 128;
        const int ns = gsn & 7;
#pragma unroll
        for (int jj = 0; jj < 2; ++jj) {
            int j = w * 2 + jj;
            int r = 16 * j + sj_r;
            int c = sj_s ^ ((r >> 1) & 3);
            gld_lds16(featbf + ((size_t)(nct + r) << 9) + 256 + ns * 32 + c * 8,
                      dst + j * 1024);
        }
    };

    stageA(0, cur);          // 2 loads in flight
    stageA(1, nxt);          // 4 loads in flight

#pragma unroll 1
    for (int ct = 0; ct < 8; ++ct) {
        const int ctbase = strip * 1024 + ct * 128;
        v4f acc[4][2];
#pragma unroll
        for (int mi = 0; mi < 4; ++mi)
#pragma unroll
            for (int ni = 0; ni < 2; ++ni) acc[mi][ni] = (v4f)0.0f;

#pragma unroll
        for (int s = 0; s < 8; ++s) {
            // counted wait (per-wave) + barrier (collective): batch gs landed
            // block-wide; batch gs+1 stays in flight across the barrier
            asm volatile("s_waitcnt vmcnt(2)" ::: "memory");
            asm volatile("s_barrier" ::: "memory");
            {   // prefetch gs+2 into the buffer all waves finished (gs-1)
                int gsn = ct * 8 + s + 2;
                if (gsn > 63) gsn = 63;   // dummy (never read); keeps count uniform
                stageA(gsn, fre);
            }
            // compute current batch
            s8b a[4];
#pragma unroll
            for (int mi = 0; mi < 4; ++mi)
                a[mi] = *(const s8b*)(cur + (wx * 64 + mi * 16 + lane16) * 64 + akey);
#pragma unroll
            for (int ni = 0; ni < 2; ++ni)
#pragma unroll
                for (int mi = 0; mi < 4; ++mi)
                    acc[mi][ni] = __builtin_amdgcn_mfma_f32_16x16x32_bf16(
                        a[mi], bfr[ni * 8 + s], acc[mi][ni], 0, 0, 0);
            char* tmp = cur; cur = nxt; nxt = fre; fre = tmp;   // rotate
        }
        // ---- batch scan: pack (ni0,ni1) pairs -> one packed sort + merge ----
        const bool dohere = dstrip && (ct == dct);   // wave-uniform
        h2 nw[16];
        if (dohere) {   // diagonal mask: only 1 of 64 (strip,ct) batches
            const int row0 = nbase + wy * 32 + lane16;   // ni=0 row; ni=1 is +16
#pragma unroll
            for (int mi = 0; mi < 4; ++mi) {
                const int c0 = ctbase + wx * 64 + mi * 16 + quad * 4;
#pragma unroll
                for (int r4 = 0; r4 < 4; ++r4) {
                    float v0 = acc[mi][0][r4];
                    float v1 = acc[mi][1][r4];
                    if (c0 + r4 == row0) v0 = -INFINITY;
                    if (c0 + r4 == row0 + 16) v1 = -INFINITY;
                    nw[mi * 4 + r4] = pk2(v0, v1);
                }
            }
        } else {
#pragma unroll
            for (int mi = 0; mi < 4; ++mi)
#pragma unroll
                for (int r4 = 0; r4 < 4; ++r4)
                    nw[mi * 4 + r4] = pk2(acc[mi][0][r4], acc[mi][1][r4]);
        }
        sort16p(nw);
        merge2_top16(lst, nw);
    }
    // ---- quad merge via xor-shfl (both ni lists travel together) ----
#pragma unroll
    for (int r = 16; r <= 32; r <<= 1) {
        h2 nw[16];
#pragma unroll
        for (int i = 0; i < 16; ++i) nw[i] = shfl2(lst[i], l ^ r);
        merge2_top16(lst, nw);
    }
    // ---- wx merge via LDS (full __syncthreads drains dummy prefetches) ----
    __syncthreads();
    h2* mrg = (h2*)smem;   // 32 row-pairs x 16 h2 = 2 KB
    if (wx == 1 && quad == 0) {
        const int rl = wy * 16 + lane16;
#pragma unroll
        for (int i = 0; i < 16; ++i) mrg[rl * 16 + i] = lst[i];
    }
    __syncthreads();
    if (wx == 0 && quad == 0) {
        const int rl = wy * 16 + lane16;
        h2 nw[16];
#pragma unroll
        for (int i = 0; i < 16; ++i) nw[i] = mrg[rl * 16 + i];
        merge2_top16(lst, nw);
        // unpack both ni rows to f32 workspace (ascending, stage2 format kept)
#pragma unroll
        for (int ni = 0; ni < 2; ++ni) {
            const int grow = nbase + wy * 32 + ni * 16 + lane16;
            float* dst = wsTop + ((size_t)grow * NSTRIPS + strip) * 16;
#pragma unroll
            for (int i = 0; i < 16; i += 4)
                *(float4*)(dst + i) = make_float4((float)lst[i][ni], (float)lst[i + 1][ni],
                                                  (float)lst[i + 2][ni], (float)lst[i + 3][ni]);
        }
    }
}

// ------- stage2: 2 threads/row, merge 8 sorted lists -> top-16 -> partials ----
__global__ void stage2_fast(const float* __restrict__ wsTop, float* __restrict__ partialNeg) {
    __shared__ float red[128];
    int tid = blockIdx.x * 128 + threadIdx.x;   // 16384 threads, 128 blocks
    int row = tid >> 1, half = tid & 1;
    const float* src = wsTop + (size_t)row * (NSTRIPS * 16) + half * 64;
    float lst[16];
#pragma unroll
    for (int i = 0; i < 16; ++i) lst[i] = src[i];
#pragma unroll
    for (int c = 16; c < 64; c += 16) {
        float nw[16];
#pragma unroll
        for (int i = 0; i < 16; ++i) nw[i] = src[c + i];
        merge_top16(lst, nw);
    }
    {   // partner merge (adjacent lane, same wave)
        float nw[16];
        int pl = (threadIdx.x & 63) ^ 1;
#pragma unroll
        for (int i = 0; i < 16; ++i) nw[i] = __shfl(lst[i], pl, 64);
        merge_top16(lst, nw);
    }
    float s = 0.0f;
#pragma unroll
    for (int i = 0; i < 16; ++i) s += sat_exp(lst[i]);
    red[threadIdx.x] = half ? 0.0f : s;
    __syncthreads();
    for (int o = 64; o; o >>= 1) {
        if (threadIdx.x < o) red[threadIdx.x] += red[threadIdx.x + o];
        __syncthreads();
    }
    if (threadIdx.x == 0) partialNeg[blockIdx.x] = red[0];
}

// ---------------- final: reduce partials, sanitize inf/nan ----------------
__global__ void final_kernel(const float* __restrict__ partialPos,
                             const float* __restrict__ partialNeg,
                             float* __restrict__ out) {
    __shared__ float w1[4], w2[4];
    float sp = 0.0f, sn = 0.0f;
    for (int i = threadIdx.x; i < 1024; i += 256) sp += partialPos[i];
    if (threadIdx.x < 128) sn = partialNeg[threadIdx.x];
#pragma unroll
    for (int o = 32; o; o >>= 1) {
        sp += __shfl_xor(sp, o, 64);
        sn += __shfl_xor(sn, o, 64);
    }
    if ((threadIdx.x & 63) == 0) {
        w1[threadIdx.x >> 6] = sp;
        w2[threadIdx.x >> 6] = sn;
    }
    __syncthreads();
    if (threadIdx.x == 0) {
        float tp = w1[0] + w1[1] + w1[2] + w1[3];
        float tn = w2[0] + w2[1] + w2[2] + w2[3];
        out[0] = finite_or(-(tp / (float)BS), 0.0f);
        out[1] = finite_or(tn / (float)(BS * KNEG), 0.0f);
    }
}

// ======================= legacy fallback (ws too small) ======================
__global__ void init_acc(float* acc) {
    if (threadIdx.x < 64) acc[threadIdx.x] = 0.0f;
}

__global__ void pos_kernel(const float* __restrict__ feat, float* __restrict__ acc) {
    int t = blockIdx.x * 256 + threadIdx.x;
    int row = t >> 4;
    int lane16 = t & 15;
    const float* f = feat + (size_t)row * 512 + lane16 * 16;
    float p = 0.0f;
#pragma unroll
    for (int q = 0; q < 16; q += 4) {
        float4 a = *(const float4*)(f + q);
        float4 b = *(const float4*)(f + 256 + q);
        p += a.x * b.x + a.y * b.y + a.z * b.z + a.w * b.w;
    }
#pragma unroll
    for (int o = 8; o; o >>= 1) p += __shfl_xor(p, o, 16);
    if (lane16 == 0) atomicAdd(&acc[0], sat_exp(p));
}

#define L_AOFF   0
#define L_BOFF   10240
#define L_PITCH  80
#define CPITCH  272
#define CWAVE   17408
#define L_SMEM  69632
__global__ __launch_bounds__(256, 2) void stage1_legacy(const float* __restrict__ feat,
                                                        float* __restrict__ wsTop) {
    __shared__ __align__(16) char smem[L_SMEM];
    const int t = threadIdx.x;
    const int l = t & 63;
    const int w = t >> 6;
    const int wy = w >> 1, wx = w & 1;
    const int quad = l >> 4, lane16 = l & 15;
    const int rowbase = blockIdx.x * 128;
    const int strip = blockIdx.y;
    char* cw = smem + w * CWAVE;
    const int grow = rowbase + wy * 64 + l;

    float lst[16];
#pragma unroll
    for (int i = 0; i < 16; ++i) lst[i] = -INFINITY;

    for (int ct = 0; ct < 4; ++ct) {
        const int colbase = strip * 1024 + ct * 256;
        v4f acc[4][8];
#pragma unroll
        for (int mi = 0; mi < 4; ++mi)
#pragma unroll
            for (int ni = 0; ni < 8; ++ni) acc[mi][ni] = (v4f)0.0f;
        for (int s = 0; s < 8; ++s) {
            const int k0 = s * 32;
            __syncthreads();
#pragma unroll
            for (int i = 0; i < 4; ++i) {
                int c = i * 256 + t;
                int r = c >> 3, chk = c & 7;
                float4 v = *(const float4*)(feat + (size_t)(rowbase + r) * 512 + k0 + chk * 4);
                uint2 pk;
                pk.x = (unsigned)f2bf_rne(v.x) | ((unsigned)f2bf_rne(v.y) << 16);
                pk.y = (unsigned)f2bf_rne(v.z) | ((unsigned)f2bf_rne(v.w) << 16);
                *(uint2*)(smem + L_AOFF + r * L_PITCH + chk * 8) = pk;
            }
#pragma unroll
            for (int i = 0; i < 8; ++i) {
                int c = i * 256 + t;
                int n = c >> 3, chk = c & 7;
                float4 v = *(const float4*)(feat + (size_t)(colbase + n) * 512 + 256 + k0 + chk * 4);
                uint2 pk;
                pk.x = (unsigned)f2bf_rne(v.x) | ((unsigned)f2bf_rne(v.y) << 16);
                pk.y = (unsigned)f2bf_rne(v.z) | ((unsigned)f2bf_rne(v.w) << 16);
                *(uint2*)(smem + L_BOFF + n * L_PITCH + chk * 8) = pk;
            }
            __syncthreads();
            s8b a[4];
#pragma unroll
            for (int mi = 0; mi < 4; ++mi)
                a[mi] = *(const s8b*)(smem + L_AOFF + (wy * 64 + mi * 16 + lane16) * L_PITCH + quad * 16);
#pragma unroll
            for (int ni = 0; ni < 8; ++ni) {
                s8b b = *(const s8b*)(smem + L_BOFF + (wx * 128 + ni * 16 + lane16) * L_PITCH + quad * 16);
#pragma unroll
                for (int mi = 0; mi < 4; ++mi)
                    acc[mi][ni] = __builtin_amdgcn_mfma_f32_16x16x32_bf16(a[mi], b, acc[mi][ni], 0, 0, 0);
            }
        }
#pragma unroll
        for (int h = 0; h < 2; ++h) {
            __syncthreads();
#pragma unroll
            for (int ni = 0; ni < 4; ++ni) {
                int c = ni * 16 + lane16;
#pragma unroll
                for (int mi = 0; mi < 4; ++mi)
                    *(v4f*)(cw + c * CPITCH + mi * 64 + quad * 16) = acc[mi][h * 4 + ni];
            }
            __syncthreads();
            const int gc0 = colbase + wx * 128 + h * 64;
            const int dj = grow - gc0;
#pragma unroll
            for (int j = 0; j < 64; ++j) {
                float v = *(const float*)(cw + j * CPITCH + l * 4);
                if (v > lst[0] && j != dj) topk_insert(lst, v);
            }
        }
    }
    float* dst = wsTop + (size_t)grow * 256 + strip * 32 + wx * 16;
#pragma unroll
    for (int i = 0; i < 16; i += 4)
        *(float4*)(dst + i) = make_float4(lst[i], lst[i + 1], lst[i + 2], lst[i + 3]);
}

__global__ void stage2_legacy(const float* __restrict__ wsTop, float* __restrict__ acc) {
    int row = blockIdx.x * blockDim.x + threadIdx.x;
    if (row >= BS) return;
    const float* src = wsTop + (size_t)row * 256;
    float lst[16];
#pragma unroll
    for (int i = 0; i < 16; ++i) lst[i] = -INFINITY;
    for (int c = 0; c < 256; c += 4) {
        float4 v4 = *(const float4*)(src + c);
        float vv[4] = {v4.x, v4.y, v4.z, v4.w};
#pragma unroll
        for (int j = 0; j < 4; ++j)
            if (vv[j] > lst[0]) topk_insert(lst, vv[j]);
    }
    float s = 0.0f;
#pragma unroll
    for (int i = 0; i < 16; ++i) s += sat_exp(lst[i]);
    atomicAdd(&acc[1], s);
}

__global__ void final_legacy(const float* __restrict__ acc, float* __restrict__ out) {
    if (threadIdx.x == 0) {
        out[0] = finite_or(-(acc[0] / (float)BS), 0.0f);
        out[1] = finite_or(acc[1] / (float)(BS * KNEG), 0.0f);
    }
}

extern "C" void kernel_launch(void* const* d_in, const int* in_sizes, int n_in,
                              void* d_out, int out_size, void* d_ws, size_t ws_size,
                              hipStream_t stream) {
    const float* feat = (const float*)d_in[0];
    float* out = (float*)d_out;

    // layout: featbf 8 MB | wsTop 4 MB | partialPos 4 KB | partialNeg 512 B
    unsigned short* featbf = (unsigned short*)d_ws;
    float* wsTop = (float*)(featbf + (size_t)BS * 512);
    float* partialPos = wsTop + (size_t)BS * NSTRIPS * 16;
    float* partialNeg = partialPos + 1024;
    const size_t need_new = (size_t)BS * 512 * 2 + (size_t)BS * NSTRIPS * 16 * 4
                          + (1024 + 128) * 4;

    if (ws_size >= need_new) {
        conv_pos<<<1024, 256, 0, stream>>>(feat, featbf, partialPos);
        stage1<<<dim3(128, NSTRIPS), 256, 0, stream>>>(featbf, wsTop);
        stage2_fast<<<128, 128, 0, stream>>>(wsTop, partialNeg);
        final_kernel<<<1, 256, 0, stream>>>(partialPos, partialNeg, out);
    } else {
        float* acc = (float*)d_ws;
        float* wsTopL = acc + 64;   // 8 MB legacy layout
        init_acc<<<1, 64, 0, stream>>>(acc);
        pos_kernel<<<512, 256, 0, stream>>>(feat, acc);
        stage1_legacy<<<dim3(64, 8), 256, 0, stream>>>(feat, wsTopL);
        stage2_legacy<<<32, 256, 0, stream>>>(wsTopL, acc);
        final_legacy<<<1, 1, 0, stream>>>(acc, out);
    }
}

// Round 14
// 115.549 us; speedup vs baseline: 1.0355x; 1.0355x over previous
//
#include <hip/hip_runtime.h>
#include <math.h>

#define BS   8192
#define DIM  256
#define KNEG 16
#define GAMMA (1.0f / 0.07f)
#define EXP_CLAMP 60.0f   // e^60*8192*16 ~ 1.5e31 < FLT_MAX: sums stay finite
#define NSTRIPS 8

typedef float v4f  __attribute__((ext_vector_type(4)));
typedef short s8b  __attribute__((ext_vector_type(8)));   // 8 bf16 as shorts
typedef _Float16 h2 __attribute__((ext_vector_type(2)));  // packed pair (ni0, ni1)

__device__ __forceinline__ float sat_exp(float dot) {
    float a = 2.0f * GAMMA * dot - 2.0f * GAMMA;
    return expf(fminf(a, EXP_CLAMP));
}

// pack two f32 -> two f16 (v_cvt_pkrtz_f16_f32), bit-cast to our h2 type
__device__ __forceinline__ h2 pk2(float a, float b) {
    return __builtin_bit_cast(h2, __builtin_amdgcn_cvt_pkrtz(a, b));
}

// compare-exchange: x=min, y=max (2 VALU, no selects)
__device__ __forceinline__ void ce(float& x, float& y) {
    float lo = fminf(x, y), hi = fmaxf(x, y);
    x = lo; y = hi;
}

// packed compare-exchange: both halves independently (v_pk_min/max_f16)
__device__ __forceinline__ void ce2(h2& x, h2& y) {
    h2 lo = __builtin_elementwise_min(x, y);
    h2 hi = __builtin_elementwise_max(x, y);
    x = lo; y = hi;
}

// Batcher odd-even merge sort, 16 packed inputs, ascending per half. 63 CE.
__device__ __forceinline__ void sort16p(h2 (&a)[16]) {
    ce2(a[0],a[1]); ce2(a[2],a[3]); ce2(a[4],a[5]); ce2(a[6],a[7]);
    ce2(a[8],a[9]); ce2(a[10],a[11]); ce2(a[12],a[13]); ce2(a[14],a[15]);
    ce2(a[0],a[2]); ce2(a[1],a[3]); ce2(a[4],a[6]); ce2(a[5],a[7]);
    ce2(a[8],a[10]); ce2(a[9],a[11]); ce2(a[12],a[14]); ce2(a[13],a[15]);
    ce2(a[1],a[2]); ce2(a[5],a[6]); ce2(a[9],a[10]); ce2(a[13],a[14]);
    ce2(a[0],a[4]); ce2(a[1],a[5]); ce2(a[2],a[6]); ce2(a[3],a[7]);
    ce2(a[8],a[12]); ce2(a[9],a[13]); ce2(a[10],a[14]); ce2(a[11],a[15]);
    ce2(a[2],a[4]); ce2(a[3],a[5]); ce2(a[10],a[12]); ce2(a[11],a[13]);
    ce2(a[1],a[2]); ce2(a[3],a[4]); ce2(a[5],a[6]);
    ce2(a[9],a[10]); ce2(a[11],a[12]); ce2(a[13],a[14]);
    ce2(a[0],a[8]); ce2(a[1],a[9]); ce2(a[2],a[10]); ce2(a[3],a[11]);
    ce2(a[4],a[12]); ce2(a[5],a[13]); ce2(a[6],a[14]); ce2(a[7],a[15]);
    ce2(a[4],a[8]); ce2(a[5],a[9]); ce2(a[6],a[10]); ce2(a[7],a[11]);
    ce2(a[2],a[4]); ce2(a[3],a[5]); ce2(a[6],a[8]); ce2(a[7],a[9]);
    ce2(a[10],a[12]); ce2(a[11],a[13]);
    ce2(a[1],a[2]); ce2(a[3],a[4]); ce2(a[5],a[6]); ce2(a[7],a[8]);
    ce2(a[9],a[10]); ce2(a[11],a[12]); ce2(a[13],a[14]);
}

// merge two ascending sorted-16 (packed), keep top-16 ascending (16 max + 32 CE)
__device__ __forceinline__ void merge2_top16(h2 (&lst)[16], const h2 (&nw)[16]) {
#pragma unroll
    for (int i = 0; i < 16; ++i)
        lst[i] = __builtin_elementwise_max(lst[i], nw[15 - i]);
#pragma unroll
    for (int j = 8; j > 0; j >>= 1)
#pragma unroll
        for (int i = 0; i < 16; ++i) {
            int ixj = i ^ j;
            if (ixj > i) ce2(lst[i], lst[ixj]);
        }
}

// f32 merge kept for stage2 (reads f32 workspace lists)
__device__ __forceinline__ void merge_top16(float (&lst)[16], const float (&nw)[16]) {
#pragma unroll
    for (int i = 0; i < 16; ++i) lst[i] = fmaxf(lst[i], nw[15 - i]);
#pragma unroll
    for (int j = 8; j > 0; j >>= 1)
#pragma unroll
        for (int i = 0; i < 16; ++i) {
            int ixj = i ^ j;
            if (ixj > i) ce(lst[i], lst[ixj]);
        }
}

// legacy insertion helper (fallback path only)
__device__ __forceinline__ void topk_insert(float (&lst)[16], float v) {
    float nl[16];
#pragma unroll
    for (int u = 0; u < 15; ++u)
        nl[u] = (v > lst[u + 1]) ? lst[u + 1] : ((v > lst[u]) ? v : lst[u]);
    nl[15] = (v > lst[15]) ? v : lst[15];
#pragma unroll
    for (int u = 0; u < 16; ++u) lst[u] = nl[u];
}

__device__ __forceinline__ unsigned short f2bf_rne(float f) {
    unsigned int u = __float_as_uint(f);
    u += 0x7FFFu + ((u >> 16) & 1u);
    return (unsigned short)(u >> 16);
}

__device__ __forceinline__ void gld_lds16(const void* g, void* l) {
    __builtin_amdgcn_global_load_lds(
        (const __attribute__((address_space(1))) void*)g,
        (__attribute__((address_space(3))) void*)l, 16, 0, 0);
}

__device__ __forceinline__ float finite_or(float x, float repl) {
    if (isnan(x)) return repl;
    if (isinf(x)) return x > 0.0f ? 3.0e38f : -3.0e38f;
    return x;
}

__device__ __forceinline__ h2 shfl2(h2 x, int src) {
    float f = __builtin_bit_cast(float, x);
    f = __shfl(f, src, 64);
    return __builtin_bit_cast(h2, f);
}

// ------- conv_pos: fp32 -> bf16 pre-convert + per-block diagonal partials -----
__global__ void conv_pos(const float* __restrict__ feat,
                         unsigned short* __restrict__ featbf,
                         float* __restrict__ partialPos) {
    __shared__ float red[8];
    int t = blockIdx.x * 256 + threadIdx.x;   // 0..262143
    int row = t >> 5;
    int c = t & 31;                           // 8-float chunk within the 256-dim
    const float* f1 = feat + (size_t)row * 512 + c * 8;
    const float* f2 = f1 + 256;
    float4 a0 = *(const float4*)(f1);
    float4 a1 = *(const float4*)(f1 + 4);
    float4 b0 = *(const float4*)(f2);
    float4 b1 = *(const float4*)(f2 + 4);
    uint4 pa, pb;
    pa.x = (unsigned)f2bf_rne(a0.x) | ((unsigned)f2bf_rne(a0.y) << 16);
    pa.y = (unsigned)f2bf_rne(a0.z) | ((unsigned)f2bf_rne(a0.w) << 16);
    pa.z = (unsigned)f2bf_rne(a1.x) | ((unsigned)f2bf_rne(a1.y) << 16);
    pa.w = (unsigned)f2bf_rne(a1.z) | ((unsigned)f2bf_rne(a1.w) << 16);
    pb.x = (unsigned)f2bf_rne(b0.x) | ((unsigned)f2bf_rne(b0.y) << 16);
    pb.y = (unsigned)f2bf_rne(b0.z) | ((unsigned)f2bf_rne(b0.w) << 16);
    pb.z = (unsigned)f2bf_rne(b1.x) | ((unsigned)f2bf_rne(b1.y) << 16);
    pb.w = (unsigned)f2bf_rne(b1.z) | ((unsigned)f2bf_rne(b1.w) << 16);
    *(uint4*)(featbf + (size_t)row * 512 + c * 8) = pa;
    *(uint4*)(featbf + (size_t)row * 512 + 256 + c * 8) = pb;
    float p = a0.x * b0.x + a0.y * b0.y + a0.z * b0.z + a0.w * b0.w
            + a1.x * b1.x + a1.y * b1.y + a1.z * b1.z + a1.w * b1.w;
#pragma unroll
    for (int o = 16; o; o >>= 1) p += __shfl_xor(p, o, 32);
    if (c == 0) red[threadIdx.x >> 5] = sat_exp(p);
    __syncthreads();
    if (threadIdx.x == 0) {
        float s = 0.0f;
#pragma unroll
        for (int i = 0; i < 8; ++i) s += red[i];
        partialPos[blockIdx.x] = s;
    }
}

// ---------------- stage1: R10 verified best (52.4us) -------------------------
// Block 256 thr = 4 waves (wy=row-half, wx=col-half). 16x16x32 MFMA.
// B (64 F1 rows x K=256) staged once (xor-swizzled), frags hoisted to regs;
// B's dead 32KB LDS is aliased as two of THREE rotating 16KB A buffers
// (buf0 lives at A_OFF). Each batch = 128 cols x 64 k (two 8KB halves).
// Per batch (32 total): s_waitcnt vmcnt(4); s_barrier -> batch bs complete,
// bs+1 stays in flight across the barrier (T4); issue bs+2; 2 k-sub-steps x
// 8 MFMA. vmcnt retires oldest-first (m135). Tail issues clamped dummy
// prefetches (uniform count); epilogue __syncthreads drains them.
// Occupancy is register-bound at 3 waves/SIMD (state ~160 unified regs);
// R6/R13 proved neither launch_bounds(,4) nor 32KB LDS moves it.
#define A_OFF  32768
#define S1_LDS 49152

__global__ __launch_bounds__(256, 3) void stage1(const unsigned short* __restrict__ featbf,
                                                 float* __restrict__ wsTop) {
    __shared__ __align__(16) char smem[S1_LDS];
    const int t = threadIdx.x;
    const int l = t & 63;
    const int w = t >> 6;
    const int wy = w >> 1, wx = w & 1;
    const int quad = l >> 4, lane16 = l & 15;
    const int nbase = blockIdx.x * 64;
    const int strip = blockIdx.y;
    // diagonal lives only in this strip/ct (64 rows never straddle a 128-col ct)
    const bool dstrip = (strip == (nbase >> 10));
    const int dct = (nbase & 1023) >> 7;

    // ---- stage B resident: rows nbase..nbase+63 (F1), all K, swizzled ----
#pragma unroll
    for (int jj = 0; jj < 8; ++jj) {
        int j = w * 8 + jj;
        int r = 2 * j + (l >> 5);
        int c = (l & 31) ^ (r & 31);
        gld_lds16(featbf + ((size_t)(nbase + r) << 9) + c * 8, smem + j * 1024);
    }

    h2 lst[16];
    const h2 NINF = __builtin_bit_cast(h2, 0xFC00FC00u);   // (-inf, -inf)
#pragma unroll
    for (int i = 0; i < 16; ++i) lst[i] = NINF;

    const int akey = (quad ^ ((lane16 >> 1) & 3)) * 16;   // A frag slot offset
    const int sj_r = l >> 2;                              // A staging row-in-group
    const int sj_s = l & 3;                               // A staging slot

    // 3 rotating A buffers (16KB each = two 8KB halves, block-coop staging)
    char* cur = smem + A_OFF;    // holds batch bs
    char* nxt = smem;            // holds bs+1 (aliases dead B region)
    char* fre = smem + 16384;    // free      (aliases dead B region)

    // stage one 128x64 A batch (global batch bsn in [0,32)) into dst
    auto stageA = [&](int bsn, char* dst) {
        const int nct = strip * 1024 + (bsn >> 2) * 128;
        const int s0 = (bsn & 3) * 2;
#pragma unroll
        for (int half = 0; half < 2; ++half)
#pragma unroll
            for (int jj = 0; jj < 2; ++jj) {
                int j = w * 2 + jj;
                int r = 16 * j + sj_r;
                int c = sj_s ^ ((r >> 1) & 3);
                gld_lds16(featbf + ((size_t)(nct + r) << 9) + 256 + (s0 + half) * 32 + c * 8,
                          dst + half * 8192 + j * 1024);
            }
    };

    stageA(0, cur);          // batch 0 -> buf0 (non-aliasing, safe with B in flight)

    __syncthreads();         // drains B + batch0 (vmcnt 0), all staged

    // ---- B fragments -> registers, once ----
    s8b bfr[16];   // [ni*8 + s]
#pragma unroll
    for (int ni = 0; ni < 2; ++ni) {
        const int n31 = ni * 16 + lane16;
#pragma unroll
        for (int s = 0; s < 8; ++s)
            bfr[ni * 8 + s] = *(const s8b*)(smem
                + (wy * 32 + n31) * 512 + (((s * 4 + quad) ^ n31) & 31) * 16);
    }

    __syncthreads();         // all waves done reading B region -> aliasable

    stageA(1, nxt);          // batch 1 in flight (4 loads/wave outstanding)

#pragma unroll 1
    for (int ct = 0; ct < 8; ++ct) {
        const int ctbase = strip * 1024 + ct * 128;
        v4f acc[4][2];
#pragma unroll
        for (int mi = 0; mi < 4; ++mi)
#pragma unroll
            for (int ni = 0; ni < 2; ++ni) acc[mi][ni] = (v4f)0.0f;

#pragma unroll
        for (int cs = 0; cs < 4; ++cs) {
            // counted wait: batch bs complete; batch bs+1 (4 loads) in flight
            asm volatile("s_waitcnt vmcnt(4)" ::: "memory");
            asm volatile("s_barrier" ::: "memory");
            {   // prefetch bs+2 into the buffer all waves just finished (bs-1)
                int bsn = ct * 4 + cs + 2;
                if (bsn > 31) bsn = 31;   // dummy (never read); keeps count uniform
                stageA(bsn, fre);
            }
            // compute current batch: two k-sub-steps from the two 8KB halves
#pragma unroll
            for (int h = 0; h < 2; ++h) {
                const int s = cs * 2 + h;
                const char* Ab = cur + h * 8192;
                s8b a[4];
#pragma unroll
                for (int mi = 0; mi < 4; ++mi)
                    a[mi] = *(const s8b*)(Ab + (wx * 64 + mi * 16 + lane16) * 64 + akey);
#pragma unroll
                for (int ni = 0; ni < 2; ++ni)
#pragma unroll
                    for (int mi = 0; mi < 4; ++mi)
                        acc[mi][ni] = __builtin_amdgcn_mfma_f32_16x16x32_bf16(
                            a[mi], bfr[ni * 8 + s], acc[mi][ni], 0, 0, 0);
            }
            char* tmp = cur; cur = nxt; nxt = fre; fre = tmp;   // rotate
        }
        // ---- batch scan: pack (ni0,ni1) pairs -> one packed sort + merge ----
        const bool dohere = dstrip && (ct == dct);   // wave-uniform
        h2 nw[16];
        if (dohere) {   // diagonal mask: only 1 of 64 (strip,ct) batches
            const int row0 = nbase + wy * 32 + lane16;   // ni=0 row; ni=1 is +16
#pragma unroll
            for (int mi = 0; mi < 4; ++mi) {
                const int c0 = ctbase + wx * 64 + mi * 16 + quad * 4;
#pragma unroll
                for (int r4 = 0; r4 < 4; ++r4) {
                    float v0 = acc[mi][0][r4];
                    float v1 = acc[mi][1][r4];
                    if (c0 + r4 == row0) v0 = -INFINITY;
                    if (c0 + r4 == row0 + 16) v1 = -INFINITY;
                    nw[mi * 4 + r4] = pk2(v0, v1);
                }
            }
        } else {
#pragma unroll
            for (int mi = 0; mi < 4; ++mi)
#pragma unroll
                for (int r4 = 0; r4 < 4; ++r4)
                    nw[mi * 4 + r4] = pk2(acc[mi][0][r4], acc[mi][1][r4]);
        }
        sort16p(nw);
        merge2_top16(lst, nw);
    }
    // ---- quad merge via xor-shfl (both ni lists travel together) ----
#pragma unroll
    for (int r = 16; r <= 32; r <<= 1) {
        h2 nw[16];
#pragma unroll
        for (int i = 0; i < 16; ++i) nw[i] = shfl2(lst[i], l ^ r);
        merge2_top16(lst, nw);
    }
    // ---- wx merge via LDS (full __syncthreads drains dummy prefetches) ----
    __syncthreads();
    h2* mrg = (h2*)(smem + A_OFF);   // 32 row-pairs x 16 h2 = 2 KB
    if (wx == 1 && quad == 0) {
        const int rl = wy * 16 + lane16;
#pragma unroll
        for (int i = 0; i < 16; ++i) mrg[rl * 16 + i] = lst[i];
    }
    __syncthreads();
    if (wx == 0 && quad == 0) {
        const int rl = wy * 16 + lane16;
        h2 nw[16];
#pragma unroll
        for (int i = 0; i < 16; ++i) nw[i] = mrg[rl * 16 + i];
        merge2_top16(lst, nw);
        // unpack both ni rows to f32 workspace (ascending, stage2 format kept)
#pragma unroll
        for (int ni = 0; ni < 2; ++ni) {
            const int grow = nbase + wy * 32 + ni * 16 + lane16;
            float* dst = wsTop + ((size_t)grow * NSTRIPS + strip) * 16;
#pragma unroll
            for (int i = 0; i < 16; i += 4)
                *(float4*)(dst + i) = make_float4((float)lst[i][ni], (float)lst[i + 1][ni],
                                                  (float)lst[i + 2][ni], (float)lst[i + 3][ni]);
        }
    }
}

// ------- stage2: 2 threads/row, merge 8 sorted lists -> top-16 -> partials ----
__global__ void stage2_fast(const float* __restrict__ wsTop, float* __restrict__ partialNeg) {
    __shared__ float red[128];
    int tid = blockIdx.x * 128 + threadIdx.x;   // 16384 threads, 128 blocks
    int row = tid >> 1, half = tid & 1;
    const float* src = wsTop + (size_t)row * (NSTRIPS * 16) + half * 64;
    float lst[16];
#pragma unroll
    for (int i = 0; i < 16; ++i) lst[i] = src[i];
#pragma unroll
    for (int c = 16; c < 64; c += 16) {
        float nw[16];
#pragma unroll
        for (int i = 0; i < 16; ++i) nw[i] = src[c + i];
        merge_top16(lst, nw);
    }
    {   // partner merge (adjacent lane, same wave)
        float nw[16];
        int pl = (threadIdx.x & 63) ^ 1;
#pragma unroll
        for (int i = 0; i < 16; ++i) nw[i] = __shfl(lst[i], pl, 64);
        merge_top16(lst, nw);
    }
    float s = 0.0f;
#pragma unroll
    for (int i = 0; i < 16; ++i) s += sat_exp(lst[i]);
    red[threadIdx.x] = half ? 0.0f : s;
    __syncthreads();
    for (int o = 64; o; o >>= 1) {
        if (threadIdx.x < o) red[threadIdx.x] += red[threadIdx.x + o];
        __syncthreads();
    }
    if (threadIdx.x == 0) partialNeg[blockIdx.x] = red[0];
}

// ---------------- final: reduce partials, sanitize inf/nan ----------------
__global__ void final_kernel(const float* __restrict__ partialPos,
                             const float* __restrict__ partialNeg,
                             float* __restrict__ out) {
    __shared__ float w1[4], w2[4];
    float sp = 0.0f, sn = 0.0f;
    for (int i = threadIdx.x; i < 1024; i += 256) sp += partialPos[i];
    if (threadIdx.x < 128) sn = partialNeg[threadIdx.x];
#pragma unroll
    for (int o = 32; o; o >>= 1) {
        sp += __shfl_xor(sp, o, 64);
        sn += __shfl_xor(sn, o, 64);
    }
    if ((threadIdx.x & 63) == 0) {
        w1[threadIdx.x >> 6] = sp;
        w2[threadIdx.x >> 6] = sn;
    }
    __syncthreads();
    if (threadIdx.x == 0) {
        float tp = w1[0] + w1[1] + w1[2] + w1[3];
        float tn = w2[0] + w2[1] + w2[2] + w2[3];
        out[0] = finite_or(-(tp / (float)BS), 0.0f);
        out[1] = finite_or(tn / (float)(BS * KNEG), 0.0f);
    }
}

// ======================= legacy fallback (ws too small) ======================
__global__ void init_acc(float* acc) {
    if (threadIdx.x < 64) acc[threadIdx.x] = 0.0f;
}

__global__ void pos_kernel(const float* __restrict__ feat, float* __restrict__ acc) {
    int t = blockIdx.x * 256 + threadIdx.x;
    int row = t >> 4;
    int lane16 = t & 15;
    const float* f = feat + (size_t)row * 512 + lane16 * 16;
    float p = 0.0f;
#pragma unroll
    for (int q = 0; q < 16; q += 4) {
        float4 a = *(const float4*)(f + q);
        float4 b = *(const float4*)(f + 256 + q);
        p += a.x * b.x + a.y * b.y + a.z * b.z + a.w * b.w;
    }
#pragma unroll
    for (int o = 8; o; o >>= 1) p += __shfl_xor(p, o, 16);
    if (lane16 == 0) atomicAdd(&acc[0], sat_exp(p));
}

#define L_AOFF   0
#define L_BOFF   10240
#define L_PITCH  80
#define CPITCH  272
#define CWAVE   17408
#define L_SMEM  69632
__global__ __launch_bounds__(256, 2) void stage1_legacy(const float* __restrict__ feat,
                                                        float* __restrict__ wsTop) {
    __shared__ __align__(16) char smem[L_SMEM];
    const int t = threadIdx.x;
    const int l = t & 63;
    const int w = t >> 6;
    const int wy = w >> 1, wx = w & 1;
    const int quad = l >> 4, lane16 = l & 15;
    const int rowbase = blockIdx.x * 128;
    const int strip = blockIdx.y;
    char* cw = smem + w * CWAVE;
    const int grow = rowbase + wy * 64 + l;

    float lst[16];
#pragma unroll
    for (int i = 0; i < 16; ++i) lst[i] = -INFINITY;

    for (int ct = 0; ct < 4; ++ct) {
        const int colbase = strip * 1024 + ct * 256;
        v4f acc[4][8];
#pragma unroll
        for (int mi = 0; mi < 4; ++mi)
#pragma unroll
            for (int ni = 0; ni < 8; ++ni) acc[mi][ni] = (v4f)0.0f;
        for (int s = 0; s < 8; ++s) {
            const int k0 = s * 32;
            __syncthreads();
#pragma unroll
            for (int i = 0; i < 4; ++i) {
                int c = i * 256 + t;
                int r = c >> 3, chk = c & 7;
                float4 v = *(const float4*)(feat + (size_t)(rowbase + r) * 512 + k0 + chk * 4);
                uint2 pk;
                pk.x = (unsigned)f2bf_rne(v.x) | ((unsigned)f2bf_rne(v.y) << 16);
                pk.y = (unsigned)f2bf_rne(v.z) | ((unsigned)f2bf_rne(v.w) << 16);
                *(uint2*)(smem + L_AOFF + r * L_PITCH + chk * 8) = pk;
            }
#pragma unroll
            for (int i = 0; i < 8; ++i) {
                int c = i * 256 + t;
                int n = c >> 3, chk = c & 7;
                float4 v = *(const float4*)(feat + (size_t)(colbase + n) * 512 + 256 + k0 + chk * 4);
                uint2 pk;
                pk.x = (unsigned)f2bf_rne(v.x) | ((unsigned)f2bf_rne(v.y) << 16);
                pk.y = (unsigned)f2bf_rne(v.z) | ((unsigned)f2bf_rne(v.w) << 16);
                *(uint2*)(smem + L_BOFF + n * L_PITCH + chk * 8) = pk;
            }
            __syncthreads();
            s8b a[4];
#pragma unroll
            for (int mi = 0; mi < 4; ++mi)
                a[mi] = *(const s8b*)(smem + L_AOFF + (wy * 64 + mi * 16 + lane16) * L_PITCH + quad * 16);
#pragma unroll
            for (int ni = 0; ni < 8; ++ni) {
                s8b b = *(const s8b*)(smem + L_BOFF + (wx * 128 + ni * 16 + lane16) * L_PITCH + quad * 16);
#pragma unroll
                for (int mi = 0; mi < 4; ++mi)
                    acc[mi][ni] = __builtin_amdgcn_mfma_f32_16x16x32_bf16(a[mi], b, acc[mi][ni], 0, 0, 0);
            }
        }
#pragma unroll
        for (int h = 0; h < 2; ++h) {
            __syncthreads();
#pragma unroll
            for (int ni = 0; ni < 4; ++ni) {
                int c = ni * 16 + lane16;
#pragma unroll
                for (int mi = 0; mi < 4; ++mi)
                    *(v4f*)(cw + c * CPITCH + mi * 64 + quad * 16) = acc[mi][h * 4 + ni];
            }
            __syncthreads();
            const int gc0 = colbase + wx * 128 + h * 64;
            const int dj = grow - gc0;
#pragma unroll
            for (int j = 0; j < 64; ++j) {
                float v = *(const float*)(cw + j * CPITCH + l * 4);
                if (v > lst[0] && j != dj) topk_insert(lst, v);
            }
        }
    }
    float* dst = wsTop + (size_t)grow * 256 + strip * 32 + wx * 16;
#pragma unroll
    for (int i = 0; i < 16; i += 4)
        *(float4*)(dst + i) = make_float4(lst[i], lst[i + 1], lst[i + 2], lst[i + 3]);
}

__global__ void stage2_legacy(const float* __restrict__ wsTop, float* __restrict__ acc) {
    int row = blockIdx.x * blockDim.x + threadIdx.x;
    if (row >= BS) return;
    const float* src = wsTop + (size_t)row * 256;
    float lst[16];
#pragma unroll
    for (int i = 0; i < 16; ++i) lst[i] = -INFINITY;
    for (int c = 0; c < 256; c += 4) {
        float4 v4 = *(const float4*)(src + c);
        float vv[4] = {v4.x, v4.y, v4.z, v4.w};
#pragma unroll
        for (int j = 0; j < 4; ++j)
            if (vv[j] > lst[0]) topk_insert(lst, vv[j]);
    }
    float s = 0.0f;
#pragma unroll
    for (int i = 0; i < 16; ++i) s += sat_exp(lst[i]);
    atomicAdd(&acc[1], s);
}

__global__ void final_legacy(const float* __restrict__ acc, float* __restrict__ out) {
    if (threadIdx.x == 0) {
        out[0] = finite_or(-(acc[0] / (float)BS), 0.0f);
        out[1] = finite_or(acc[1] / (float)(BS * KNEG), 0.0f);
    }
}

extern "C" void kernel_launch(void* const* d_in, const int* in_sizes, int n_in,
                              void* d_out, int out_size, void* d_ws, size_t ws_size,
                              hipStream_t stream) {
    const float* feat = (const float*)d_in[0];
    float* out = (float*)d_out;

    // layout: featbf 8 MB | wsTop 4 MB | partialPos 4 KB | partialNeg 512 B
    unsigned short* featbf = (unsigned short*)d_ws;
    float* wsTop = (float*)(featbf + (size_t)BS * 512);
    float* partialPos = wsTop + (size_t)BS * NSTRIPS * 16;
    float* partialNeg = partialPos + 1024;
    const size_t need_new = (size_t)BS * 512 * 2 + (size_t)BS * NSTRIPS * 16 * 4
                          + (1024 + 128) * 4;

    if (ws_size >= need_new) {
        conv_pos<<<1024, 256, 0, stream>>>(feat, featbf, partialPos);
        stage1<<<dim3(128, NSTRIPS), 256, 0, stream>>>(featbf, wsTop);
        stage2_fast<<<128, 128, 0, stream>>>(wsTop, partialNeg);
        final_kernel<<<1, 256, 0, stream>>>(partialPos, partialNeg, out);
    } else {
        float* acc = (float*)d_ws;
        float* wsTopL = acc + 64;   // 8 MB legacy layout
        init_acc<<<1, 64, 0, stream>>>(acc);
        pos_kernel<<<512, 256, 0, stream>>>(feat, acc);
        stage1_legacy<<<dim3(64, 8), 256, 0, stream>>>(feat, wsTopL);
        stage2_legacy<<<32, 256, 0, stream>>>(wsTopL, acc);
        final_legacy<<<1, 1, 0, stream>>>(acc, out);
    }
}